// Round 1
// baseline (1263.810 us; speedup 1.0000x reference)
//
#include <hip/hip_runtime.h>
#include <math.h>

// AutoCorrelation (Autoformer) on MI355X.
// B=32, L=2048, H=16, E=64, fp32. top_k = int(log(2048)) = 7.
//
// K1: transpose q,k (B,L,H*E) -> (B,H*E,L). qT -> ws, kT -> d_out V-region (scratch).
// K2: per (b,h): 128 fwd FFTs (q,k per e, radix 8/8/8/4 DIF), accumulate
//     P = Q*conj(K) in regs, one DIT inverse -> corr row -> top-7 -> softmax.
// K3: V[b,l,h,e] = sum_i w_i * v[b,(l+d_i)%L,h,e], float4 vectorized.

#define PADI(i) ((i) + ((i) >> 5))   // LDS pad: +1 float per 32 to break pow2 strides

__device__ __forceinline__ float2 cxadd(float2 a, float2 b){ return make_float2(a.x+b.x, a.y+b.y); }
__device__ __forceinline__ float2 cxsub(float2 a, float2 b){ return make_float2(a.x-b.x, a.y-b.y); }
__device__ __forceinline__ float2 cxmul(float2 a, float2 b){ return make_float2(a.x*b.x-a.y*b.y, a.x*b.y+a.y*b.x); }
// a * conj(b)
__device__ __forceinline__ float2 cxmulc(float2 a, float2 b){ return make_float2(a.x*b.x+a.y*b.y, a.y*b.x-a.x*b.y); }

// multiply by S*i  (S=-1 forward, S=+1 inverse)
template<int S> __device__ __forceinline__ float2 mulJ(float2 x){
  return (S<0) ? make_float2(x.y, -x.x) : make_float2(-x.y, x.x);
}
// multiply by omega_8^1 (fwd: c - ic, inv: c + ic), c = sqrt(2)/2
template<int S> __device__ __forceinline__ float2 mulW1(float2 x){
  const float c = 0.70710678118654752440f;
  return (S<0)? make_float2(c*(x.x+x.y), c*(x.y-x.x)) : make_float2(c*(x.x-x.y), c*(x.x+x.y));
}
// multiply by omega_8^3
template<int S> __device__ __forceinline__ float2 mulW3(float2 x){
  const float c = 0.70710678118654752440f;
  return (S<0)? make_float2(c*(x.y-x.x), -c*(x.x+x.y)) : make_float2(-c*(x.x+x.y), c*(x.x-x.y));
}

template<int S> __device__ __forceinline__ void bfly8(float2 (&x)[8]){
  float2 t0 = cxadd(x[0], x[4]);
  float2 t1 = cxsub(x[0], x[4]);
  float2 t2 = cxadd(x[2], x[6]);
  float2 t3 = mulJ<S>(cxsub(x[2], x[6]));
  float2 t4 = cxadd(x[1], x[5]);
  float2 t5 = cxsub(x[1], x[5]);
  float2 t6 = cxadd(x[3], x[7]);
  float2 t7 = mulJ<S>(cxsub(x[3], x[7]));
  float2 e0 = cxadd(t0, t2), e1 = cxadd(t1, t3), e2 = cxsub(t0, t2), e3 = cxsub(t1, t3);
  float2 o0 = cxadd(t4, t6), o1 = cxadd(t5, t7), o2 = cxsub(t4, t6), o3 = cxsub(t5, t7);
  o1 = mulW1<S>(o1); o2 = mulJ<S>(o2); o3 = mulW3<S>(o3);
  x[0] = cxadd(e0, o0); x[4] = cxsub(e0, o0);
  x[1] = cxadd(e1, o1); x[5] = cxsub(e1, o1);
  x[2] = cxadd(e2, o2); x[6] = cxsub(e2, o2);
  x[3] = cxadd(e3, o3); x[7] = cxsub(e3, o3);
}

template<int S> __device__ __forceinline__ void bfly4(float2& a, float2& b, float2& c, float2& d){
  float2 u0 = cxadd(a, c), u1 = cxsub(a, c);
  float2 u2 = cxadd(b, d), u3 = mulJ<S>(cxsub(b, d));
  a = cxadd(u0, u2); b = cxadd(u1, u3); c = cxsub(u0, u2); d = cxsub(u1, u3);
}

// Forward 2048-pt DIF FFT (radix 8,8,8,4). Natural-order real input row (global,
// coalesced). Digit-reversed output left in x[] at logical slots 8t..8t+7.
// LDS re/im used as scratch (padded indexing). 3 barriers.
__device__ __forceinline__ void fwd_fft(const float* __restrict__ row,
                                        float* __restrict__ re, float* __restrict__ im, int t,
                                        const float2 (&w1)[8], const float2 (&w2)[8],
                                        const float2 (&w3)[8], float2 (&x)[8]) {
  // stage 1: L=2048, m=256, j=t. Input straight from global.
  #pragma unroll
  for (int r = 0; r < 8; ++r) x[r] = make_float2(row[t + (r<<8)], 0.0f);
  bfly8<-1>(x);
  #pragma unroll
  for (int p = 1; p < 8; ++p) x[p] = cxmul(x[p], w1[p]);
  #pragma unroll
  for (int p = 0; p < 8; ++p) { int i = t + (p<<8); re[PADI(i)] = x[p].x; im[PADI(i)] = x[p].y; }
  __syncthreads();
  // stage 2: L=256, m=32, j=t&31  (reads/writes same per-thread slots: no inner barrier)
  {
    int base = ((t>>5)<<8) + (t&31);
    #pragma unroll
    for (int r = 0; r < 8; ++r) { int i = base + (r<<5); x[r].x = re[PADI(i)]; x[r].y = im[PADI(i)]; }
    bfly8<-1>(x);
    #pragma unroll
    for (int p = 1; p < 8; ++p) x[p] = cxmul(x[p], w2[p]);
    #pragma unroll
    for (int p = 0; p < 8; ++p) { int i = base + (p<<5); re[PADI(i)] = x[p].x; im[PADI(i)] = x[p].y; }
  }
  __syncthreads();
  // stage 3: L=32, m=4, j=t&3
  {
    int base = ((t>>2)<<5) + (t&3);
    #pragma unroll
    for (int r = 0; r < 8; ++r) { int i = base + (r<<2); x[r].x = re[PADI(i)]; x[r].y = im[PADI(i)]; }
    bfly8<-1>(x);
    #pragma unroll
    for (int p = 1; p < 8; ++p) x[p] = cxmul(x[p], w3[p]);
    #pragma unroll
    for (int p = 0; p < 8; ++p) { int i = base + (p<<2); re[PADI(i)] = x[p].x; im[PADI(i)] = x[p].y; }
  }
  __syncthreads();
  // stage 4: radix-4, L=4, m=1, twiddle-free; two butterflies on contiguous 8t..8t+7
  {
    int base = t<<3;
    #pragma unroll
    for (int r = 0; r < 8; ++r) { int i = base + r; x[r].x = re[PADI(i)]; x[r].y = im[PADI(i)]; }
    bfly4<-1>(x[0], x[1], x[2], x[3]);
    bfly4<-1>(x[4], x[5], x[6], x[7]);
  }
}

__global__ void __launch_bounds__(256)
ac_transpose_kernel(const float* __restrict__ q, const float* __restrict__ k,
                    float* __restrict__ qT, float* __restrict__ kT) {
  // (B, L=2048, C=1024) -> (B, C, L), 64x64 tiles
  __shared__ float tile[64][65];
  const float* src = blockIdx.z ? k : q;
  float* dst       = blockIdx.z ? kT : qT;
  int t = threadIdx.x;
  int tx = t & 63, ty = t >> 6;                 // ty in 0..3
  int l0 = (blockIdx.x & 31) << 6;              // 32 l-tiles
  int c0 = (blockIdx.x >> 5) << 6;              // 16 c-tiles
  size_t b = blockIdx.y;
  const float* s = src + b * (size_t)2048 * 1024;
  float* d = dst + b * (size_t)1024 * 2048;
  #pragma unroll
  for (int rr = 0; rr < 16; ++rr) {
    int ll = ty + (rr << 2);
    tile[ll][tx] = s[(size_t)(l0 + ll) * 1024 + (c0 + tx)];
  }
  __syncthreads();
  #pragma unroll
  for (int rr = 0; rr < 16; ++rr) {
    int cc = ty + (rr << 2);
    d[(size_t)(c0 + cc) * 2048 + (l0 + tx)] = tile[tx][cc];
  }
}

__global__ void __launch_bounds__(256)
ac_corr_topk_kernel(const float* __restrict__ qT, const float* __restrict__ kT,
                    float* __restrict__ out_tc, float* __restrict__ tabw,
                    int* __restrict__ tabd) {
  __shared__ float sQr[2112], sQi[2112], sKr[2112], sKi[2112];
  __shared__ float rmax[256];
  __shared__ int   rloc[256];
  __shared__ float stv[8];
  __shared__ int   sti[8];

  const int t = threadIdx.x;
  const int bh = blockIdx.x;   // b*16 + h

  // Per-thread twiddles (depend only on t): stage1 W_2048^{t*p}, stage2 W_256^{(t&31)p},
  // stage3 W_32^{(t&3)p}. Inverse reuses them conjugated.
  float2 w1[8], w2[8], w3[8];
  w1[0] = w2[0] = w3[0] = make_float2(1.f, 0.f);
  #pragma unroll
  for (int p = 1; p < 8; ++p) {
    float s, c;
    sincosf(-6.28318530717958647692f * (float)(t * p)      * (1.0f/2048.0f), &s, &c); w1[p] = make_float2(c, s);
    sincosf(-6.28318530717958647692f * (float)((t&31) * p) * (1.0f/256.0f),  &s, &c); w2[p] = make_float2(c, s);
    sincosf(-6.28318530717958647692f * (float)((t&3) * p)  * (1.0f/32.0f),   &s, &c); w3[p] = make_float2(c, s);
  }

  float2 acc[8];
  #pragma unroll
  for (int r = 0; r < 8; ++r) acc[r] = make_float2(0.f, 0.f);

  const float* qb = qT + (size_t)bh * (64 * 2048);
  const float* kb = kT + (size_t)bh * (64 * 2048);

  #pragma unroll 1
  for (int e = 0; e < 64; ++e) {
    __syncthreads();  // guard sQ/sK rewrite vs prev-iteration cross-thread reads
    float2 x[8];
    fwd_fft(qb + e * 2048, sQr, sQi, t, w1, w2, w3, x);
    #pragma unroll
    for (int r = 0; r < 8; ++r) { int i = (t<<3) + r; sQr[PADI(i)] = x[r].x; sQi[PADI(i)] = x[r].y; }
    fwd_fft(kb + e * 2048, sKr, sKi, t, w1, w2, w3, x);
    // P += Q * conj(K), all in the same digit-reversed permutation -> elementwise valid
    #pragma unroll
    for (int r = 0; r < 8; ++r) {
      int i = (t<<3) + r;
      float Qr = sQr[PADI(i)], Qi = sQi[PADI(i)];
      acc[r].x += Qr * x[r].x + Qi * x[r].y;
      acc[r].y += Qi * x[r].x - Qr * x[r].y;
    }
  }

  // ---- inverse FFT (DIT, mirrored radices 4,8,8,8, conj twiddles, 1/N) ----
  bfly4<1>(acc[0], acc[1], acc[2], acc[3]);
  bfly4<1>(acc[4], acc[5], acc[6], acc[7]);
  __syncthreads();
  #pragma unroll
  for (int r = 0; r < 8; ++r) { int i = (t<<3) + r; sQr[PADI(i)] = acc[r].x; sQi[PADI(i)] = acc[r].y; }
  __syncthreads();
  {
    float2 x[8];
    // L=32, m=4
    int base3 = ((t>>2)<<5) + (t&3);
    #pragma unroll
    for (int r = 0; r < 8; ++r) { int i = base3 + (r<<2); x[r].x = sQr[PADI(i)]; x[r].y = sQi[PADI(i)]; }
    #pragma unroll
    for (int r = 1; r < 8; ++r) x[r] = cxmulc(x[r], w3[r]);
    bfly8<1>(x);
    #pragma unroll
    for (int p = 0; p < 8; ++p) { int i = base3 + (p<<2); sQr[PADI(i)] = x[p].x; sQi[PADI(i)] = x[p].y; }
    __syncthreads();
    // L=256, m=32
    int base2 = ((t>>5)<<8) + (t&31);
    #pragma unroll
    for (int r = 0; r < 8; ++r) { int i = base2 + (r<<5); x[r].x = sQr[PADI(i)]; x[r].y = sQi[PADI(i)]; }
    #pragma unroll
    for (int r = 1; r < 8; ++r) x[r] = cxmulc(x[r], w2[r]);
    bfly8<1>(x);
    #pragma unroll
    for (int p = 0; p < 8; ++p) { int i = base2 + (p<<5); sQr[PADI(i)] = x[p].x; sQi[PADI(i)] = x[p].y; }
    __syncthreads();
    // L=2048, m=256
    #pragma unroll
    for (int r = 0; r < 8; ++r) { int i = t + (r<<8); x[r].x = sQr[PADI(i)]; x[r].y = sQi[PADI(i)]; }
    #pragma unroll
    for (int r = 1; r < 8; ++r) x[r] = cxmulc(x[r], w1[r]);
    bfly8<1>(x);
    const float sc = 1.0f / (2048.0f * 64.0f);  // irfft 1/N  *  mean over E
    #pragma unroll
    for (int p = 0; p < 8; ++p) { int i = t + (p<<8); sQr[PADI(i)] = x[p].x * sc; }
    __syncthreads();
  }

  // ---- top-7 (descending, ties -> lowest index, matching lax.top_k) ----
  #pragma unroll 1
  for (int it = 0; it < 7; ++it) {
    float bv = -INFINITY; int bi = 0x7fffffff;
    #pragma unroll
    for (int r = 0; r < 8; ++r) {
      int i = t + (r<<8);
      float val = sQr[PADI(i)];
      if (val > bv || (val == bv && i < bi)) { bv = val; bi = i; }
    }
    rmax[t] = bv; rloc[t] = bi;
    __syncthreads();
    #pragma unroll 1
    for (int s = 128; s > 0; s >>= 1) {
      if (t < s) {
        float ov = rmax[t + s]; int oi = rloc[t + s];
        if (ov > rmax[t] || (ov == rmax[t] && oi < rloc[t])) { rmax[t] = ov; rloc[t] = oi; }
      }
      __syncthreads();
    }
    if (t == 0) { stv[it] = rmax[0]; sti[it] = rloc[0]; sQr[PADI(rloc[0])] = -INFINITY; }
    __syncthreads();
  }

  if (t == 0) {
    float m = stv[0], ssum = 0.f, w[7];
    #pragma unroll
    for (int i = 0; i < 7; ++i) { w[i] = __expf(stv[i] - m); ssum += w[i]; }
    float inv = 1.0f / ssum;
    #pragma unroll
    for (int i = 0; i < 7; ++i) {
      float wi = w[i] * inv;
      out_tc[bh * 7 + i] = wi;     // tmp_corr output (B,H,7)
      tabw[bh * 8 + i]  = wi;      // table for aggregation
      tabd[bh * 8 + i]  = sti[i];
    }
  }
}

__global__ void __launch_bounds__(256)
ac_agg_kernel(const float* __restrict__ v, const float* __restrict__ tabw,
              const int* __restrict__ tabd, float* __restrict__ out) {
  // one float4 (4 e-values) per thread; 16.7M threads total
  int gid = blockIdx.x * 256 + threadIdx.x;
  int e4 = gid & 15;
  int h  = (gid >> 4) & 15;
  int l  = (gid >> 8) & 2047;
  int b  = gid >> 19;
  int bh = (b << 4) + h;
  float w[7]; int d[7];
  #pragma unroll
  for (int i = 0; i < 7; ++i) { w[i] = tabw[bh * 8 + i]; d[i] = tabd[bh * 8 + i]; }
  float4 acc = make_float4(0.f, 0.f, 0.f, 0.f);
  #pragma unroll
  for (int i = 0; i < 7; ++i) {
    int l2 = (l + d[i]) & 2047;   // roll(v, -d)[l] = v[(l+d) mod L]
    const float4* src = (const float4*)(v + ((((size_t)b * 2048 + l2) * 16 + h) << 6));
    float4 x = src[e4];
    acc.x += w[i] * x.x; acc.y += w[i] * x.y; acc.z += w[i] * x.z; acc.w += w[i] * x.w;
  }
  ((float4*)(out + ((((size_t)b * 2048 + l) * 16 + h) << 6)))[e4] = acc;
}

extern "C" void kernel_launch(void* const* d_in, const int* in_sizes, int n_in,
                              void* d_out, int out_size, void* d_ws, size_t ws_size,
                              hipStream_t stream) {
  const float* q = (const float*)d_in[0];
  const float* k = (const float*)d_in[1];
  const float* v = (const float*)d_in[2];
  float* out = (float*)d_out;

  const size_t NELEM = (size_t)32 * 2048 * 16 * 64;  // 67,108,864

  // workspace layout: qT (256 MB) | tabw (512*8 f32) | tabd (512*8 i32)
  float* qT   = (float*)d_ws;
  float* tabw = qT + NELEM;
  int*   tabd = (int*)(tabw + 512 * 8);

  // kT lives in d_out's V region as scratch (exactly NELEM floats);
  // it is fully consumed by K2 before K3 overwrites the region.
  float* kT     = out;
  float* out_tc = out + NELEM;  // tmp_corr (B,H,7) = 3584 floats

  ac_transpose_kernel<<<dim3(512, 32, 2), 256, 0, stream>>>(q, k, qT, kT);
  ac_corr_topk_kernel<<<512, 256, 0, stream>>>(qT, kT, out_tc, tabw, tabd);
  ac_agg_kernel<<<65536, 256, 0, stream>>>(v, tabw, tabd, out);
}